// Round 1
// baseline (44.482 us; speedup 1.0000x reference)
//
#include <hip/hip_runtime.h>
#include <hip/hip_bf16.h>

#define BN 4
#define CIN 128
#define CMID 64
#define HH 64
#define WW 64
#define HW 4096
#define K2 25
#define H2 128
#define W2 128
#define HW2 16384
#define EPSN 1e-5f

typedef __attribute__((ext_vector_type(8))) short short8;
typedef __attribute__((ext_vector_type(4))) float f32x4;

__device__ inline unsigned short f2b(float f) {
  union { __hip_bfloat16 h; unsigned short u; } cv;
  cv.h = __float2bfloat16(f);
  return cv.u;
}

__device__ inline float b16f(unsigned s) {
  union { unsigned u; float f; } cv;
  cv.u = s << 16;
  return cv.f;
}

// ---------------------------------------------------------------------------
// Kernel A: per (b,h,wq) block (grid 1024, 4 waves):
//   - packs its 72-element slice of enc_w -> Wb (same layout as before)
//   - computes y = SiLU(BN(1x1conv(x))) for its 16 px ONCE (no halo), via the
//     same MFMA order as the old in-block phase 1 (bit-identical bf16 y),
//     stores bf16 y_t[b][h][w][o] (o contiguous) for coalesced re-staging in B.
// ---------------------------------------------------------------------------
__global__ __launch_bounds__(256) void compress_kernel(
    const float* __restrict__ x, const float* __restrict__ cw,
    const float* __restrict__ gamma, const float* __restrict__ beta,
    const float* __restrict__ mean, const float* __restrict__ var,
    const float* __restrict__ ew, unsigned short* __restrict__ Wb,
    unsigned short* __restrict__ yt) {
  __shared__ unsigned short xT[16 * 136];  // [w'][c], 272B rows (2-way banks)
  __shared__ float sinv[CMID], sadd[CMID];
  int t = threadIdx.x;
  int bx = blockIdx.x;
  int b = bx >> 8;
  int rem = bx & 255;
  int h = rem >> 2;
  int w0 = (rem & 3) * 16;

  // Wb pack: 73728 elems over 1024 blocks = 72 each (same formula as old pack)
  if (t < 72) {
    int i = bx * 72 + t;
    int c = i & 63;
    int n = (i >> 6) & 127;
    int tap = i >> 13;
    int q = n >> 5, k = n & 31;
    float v = (k < K2) ? ew[((k * 4 + q) * CMID + c) * 9 + tap] : 0.f;
    Wb[i] = f2b(v);
  }
  if (t < CMID) {
    float iv = gamma[t] * rsqrtf(var[t] + EPSN);
    sinv[t] = iv;
    sadd[t] = beta[t] - mean[t] * iv;
  }
  // stage xT[w'][c] bf16 (transposed so B-frag gather is one b128 per ks)
  for (int i = t; i < 512; i += 256) {
    int c = i >> 2;
    int w4 = (i & 3) * 4;
    float4 f = *(const float4*)&x[(size_t)(b * CIN + c) * HW + h * WW + w0 + w4];
    xT[(w4 + 0) * 136 + c] = f2b(f.x);
    xT[(w4 + 1) * 136 + c] = f2b(f.y);
    xT[(w4 + 2) * 136 + c] = f2b(f.z);
    xT[(w4 + 3) * 136 + c] = f2b(f.w);
  }
  __syncthreads();

  int lane = t & 63;
  int nt = __builtin_amdgcn_readfirstlane(t >> 6);  // wave owns o-block nt
  int lm = lane & 15, lg = lane >> 4;

  f32x4 acc = (f32x4){0.f, 0.f, 0.f, 0.f};
#pragma unroll
  for (int ks = 0; ks < 4; ++ks) {
    short8 bf = *(const short8*)&xT[lm * 136 + ks * 32 + lg * 8];
    short8 af;
    const float* cp = &cw[(nt * 16 + lm) * CIN + ks * 32 + lg * 8];
#pragma unroll
    for (int e = 0; e < 8; ++e) af[e] = (short)f2b(cp[e]);
    acc = __builtin_amdgcn_mfma_f32_16x16x32_bf16(af, bf, acc, 0, 0, 0);
  }

  // D layout: col=lane&15 -> w' = lm, row = lg*4+r -> o (within nt block)
  int o0 = nt * 16 + lg * 4;
  unsigned long long pk = 0;
#pragma unroll
  for (int r = 0; r < 4; ++r) {
    float v = acc[r] * sinv[o0 + r] + sadd[o0 + r];
    v = v / (1.f + __expf(-v));  // SiLU
    pk |= (unsigned long long)f2b(v) << (16 * r);
  }
  *(unsigned long long*)&yt[((size_t)(b * HH + h) * WW + w0 + lm) * CMID + o0] =
      pk;
}

// ---------------------------------------------------------------------------
// Kernel B: per (b,h,quarter) block (grid 1024, 4 waves). Phases:
//  0. stage x halo -> xl (verbatim R10 layout) AND stage y halo from yt into
//     the XOR-swizzled yl layout (coalesced uint4, zero-fill OOB).
//  1. mask MFMA (verbatim) -> ml, now compacted to [100][17] (k*4+q rows).
//  2. softmax + fold -> q3s, ALIASED onto yl (dead after phase 1).
//  3. reassembly from xl (verbatim).
// LDS: 19.5(xl) + 7.7(yl/q3s) + 6.8(ml) = 34.5 KB -> 4 blk/CU. 3 barriers.
// ---------------------------------------------------------------------------
__global__ __launch_bounds__(256) void carafe_kernel(
    const float* __restrict__ x, const unsigned short* __restrict__ Wb,
    const unsigned short* __restrict__ yt, const float* __restrict__ eb,
    float* __restrict__ out) {
  __shared__ unsigned short xl[128 * 3 * 26];          // 19.5 KB, 52B rows
  __shared__ __align__(16) unsigned short yl[3 * 20 * 64];  // 7.7 KB swizzled
  __shared__ float ml[100][17];                        // 6.8 KB logits [k*4+q][px]
  int t = threadIdx.x;
  int bx = blockIdx.x;
  int b = bx >> 8;
  int rem = bx & 255;
  int h = rem >> 2;
  int p0g = (rem & 3) * 16;

  // stage xl: 128 ch x 3 rows x 24 cols (p0g-4 .. p0g+19) as bf16, zero OOB.
  for (int i = t; i < 128 * 3 * 6; i += 256) {
    int c = i / 18;
    int r = i - c * 18;
    int dh = r / 6, j4 = r - dh * 6;
    int hh = h + dh - 1;
    int cb = p0g - 4 + 4 * j4;
    float4 f; f.x = 0.f; f.y = 0.f; f.z = 0.f; f.w = 0.f;
    if ((unsigned)hh < (unsigned)HH) {
      const float* xp = &x[(size_t)(b * CIN + c) * HW + hh * WW];
      if (cb >= 0 && cb <= WW - 4) {
        f = *(const float4*)&xp[cb];
      } else {
        float tmp[4];
#pragma unroll
        for (int e = 0; e < 4; ++e)
          tmp[e] = ((unsigned)(cb + e) < (unsigned)WW) ? xp[cb + e] : 0.f;
        f.x = tmp[0]; f.y = tmp[1]; f.z = tmp[2]; f.w = tmp[3];
      }
    }
    char* dst = (char*)xl + (c * 3 + dh) * 52 + 8 * j4;
    *(unsigned*)dst = (unsigned)f2b(f.x) | ((unsigned)f2b(f.y) << 16);
    *(unsigned*)(dst + 4) = (unsigned)f2b(f.z) | ((unsigned)f2b(f.w) << 16);
  }
  // stage yl from yt: 3 dh x 18 cols x 8 chunks of 16B, swizzled like phase 1
  // used to write it ((chunk byte) ^ ((R&7)<<4)); zero-fill OOB halo px.
  for (int i = t; i < 432; i += 256) {
    int ch = i & 7;
    int j = i >> 3;
    int dh = j / 18, cwl = j - dh * 18;
    int R = dh * 20 + cwl;
    int hh = h + dh - 1, wg = p0g - 1 + cwl;
    uint4 v; v.x = 0; v.y = 0; v.z = 0; v.w = 0;
    if ((unsigned)hh < (unsigned)HH && (unsigned)wg < (unsigned)WW)
      v = *(const uint4*)&yt[((size_t)(b * HH + hh) * WW + wg) * CMID + ch * 8];
    *(uint4*)((char*)yl + R * 128 + ((ch * 16) ^ ((R & 7) << 4))) = v;
  }
  __syncthreads();

  // ---- phase 1: mask MFMA (R6 verbatim): wave = n-quarter, 16 px ----
  {
    int lane = t & 63;
    int nq = __builtin_amdgcn_readfirstlane(t >> 6);
    int lm = lane & 15, lg = lane >> 4;

    f32x4 acc[2];
    acc[0] = (f32x4){0.f, 0.f, 0.f, 0.f};
    acc[1] = (f32x4){0.f, 0.f, 0.f, 0.f};

#pragma unroll
    for (int dh = 0; dh < 3; ++dh) {
#pragma unroll
      for (int dw = 0; dw < 3; ++dw) {
        int tap = dh * 3 + dw;
        int R = dh * 20 + lm + dw;
        char* rowp = (char*)yl + R * 128;
        int xorm = (R & 7) << 4;
        short8 a0 = *(short8*)(rowp + ((lg * 16) ^ xorm));
        short8 a1 = *(short8*)(rowp + ((64 + lg * 16) ^ xorm));
        const unsigned short* wt = Wb + tap * 8192 + lg * 8;
#pragma unroll
        for (int nti = 0; nti < 2; ++nti) {
          const unsigned short* bp = wt + ((nq * 2 + nti) * 16 + lm) * 64;
          short8 b0 = *(const short8*)bp;
          short8 b1 = *(const short8*)(bp + 32);
          acc[nti] = __builtin_amdgcn_mfma_f32_16x16x32_bf16(a0, b0, acc[nti], 0, 0, 0);
          acc[nti] = __builtin_amdgcn_mfma_f32_16x16x32_bf16(a1, b1, acc[nti], 0, 0, 0);
        }
      }
    }

#pragma unroll
    for (int nti = 0; nti < 2; ++nti) {
      int n = (nq * 2 + nti) * 16 + lm;
      int k = n & 31, q = n >> 5;
      if (k < K2) {
#pragma unroll
        for (int r = 0; r < 4; ++r) ml[k * 4 + q][lg * 4 + r] = acc[nti][r];
      }
    }
  }
  __syncthreads();

  // ---- phase 2: softmax + fold -> q3s (aliased onto yl; yl is dead) ----
  float* q3s = (float*)yl;  // [16][37]
  if (t < 64) {
    int wl = t & 15, q = t >> 4;
    int wg = p0g + wl;
    int sh = q >> 1, sw = q & 1;
    float a25[K2];
#pragma unroll
    for (int k = 0; k < K2; ++k) a25[k] = ml[k * 4 + q][wl] + eb[k * 4 + q];

    float mx = a25[0];
#pragma unroll
    for (int k = 1; k < K2; ++k) mx = fmaxf(mx, a25[k]);
    float ssum = 0.f;
#pragma unroll
    for (int k = 0; k < K2; ++k) {
      a25[k] = __expf(a25[k] - mx);
      ssum += a25[k];
    }
    float inv = 1.f / ssum;

    float rs[3][5];
    if (sh == 0) {
#pragma unroll
      for (int j = 0; j < 5; ++j) {
        rs[0][j] = a25[j] + a25[5 + j];
        rs[1][j] = a25[10 + j] + a25[15 + j];
        rs[2][j] = a25[20 + j];
      }
    } else {
#pragma unroll
      for (int j = 0; j < 5; ++j) {
        rs[0][j] = a25[j];
        rs[1][j] = a25[5 + j] + a25[10 + j];
        rs[2][j] = a25[15 + j] + a25[20 + j];
      }
    }
    float q3[3][3];
#pragma unroll
    for (int i = 0; i < 3; ++i) {
      if (sw == 0) {
        q3[i][0] = rs[i][0] + rs[i][1];
        q3[i][1] = rs[i][2] + rs[i][3];
        q3[i][2] = rs[i][4];
      } else {
        q3[i][0] = rs[i][0];
        q3[i][1] = rs[i][1] + rs[i][2];
        q3[i][2] = rs[i][3] + rs[i][4];
      }
      q3[i][0] *= inv;
      q3[i][1] *= inv;
      q3[i][2] *= inv;
    }
    if (h == 0) { q3[0][0] = q3[0][1] = q3[0][2] = 0.f; }
    if (h == HH - 1) { q3[2][0] = q3[2][1] = q3[2][2] = 0.f; }
    if (wg == 0) { q3[0][0] = q3[1][0] = q3[2][0] = 0.f; }
    if (wg == WW - 1) { q3[0][2] = q3[1][2] = q3[2][2] = 0.f; }

#pragma unroll
    for (int i = 0; i < 3; ++i)
#pragma unroll
      for (int j = 0; j < 3; ++j) q3s[wl * 37 + q * 9 + i * 3 + j] = q3[i][j];
  }
  __syncthreads();

  // ---- phase 3: reassembly from xl (R10 verbatim) ----
  {
    int wl = t & 15;
    int sh = (t >> 4) & 1;
    int cg = t >> 5;

    float m0[9], m1[9];
#pragma unroll
    for (int j = 0; j < 9; ++j) {
      m0[j] = q3s[wl * 37 + (2 * sh) * 9 + j];
      m1[j] = q3s[wl * 37 + (2 * sh + 1) * 9 + j];
    }

    int lcE = (wl + 3) & ~1;
    bool oddw = (wl & 1) != 0;

    float* ob = out + (size_t)(b * CIN + cg * 16) * HW2 +
                (size_t)(2 * h + sh) * W2 + 2 * (p0g + wl);

    for (int cp = 0; cp < 16; ++cp) {
      int c = cg * 16 + cp;
      const char* xrow = (const char*)xl + (size_t)(c * 3) * 52;
      float xv[9];
#pragma unroll
      for (int rr = 0; rr < 3; ++rr) {
        unsigned a = *(const unsigned*)(xrow + rr * 52 + 2 * lcE);
        unsigned bb = *(const unsigned*)(xrow + rr * 52 + 2 * lcE + 4);
        unsigned s0, s1, s2;
        if (oddw) {
          s0 = a & 0xffffu; s1 = a >> 16; s2 = bb & 0xffffu;
        } else {
          s0 = a >> 16; s1 = bb & 0xffffu; s2 = bb >> 16;
        }
        xv[rr * 3 + 0] = b16f(s0);
        xv[rr * 3 + 1] = b16f(s1);
        xv[rr * 3 + 2] = b16f(s2);
      }
      float o0 = 0.f, o1 = 0.f;
#pragma unroll
      for (int j = 0; j < 9; ++j) {
        o0 += m0[j] * xv[j];
        o1 += m1[j] * xv[j];
      }
      float2 st = {o0, o1};
      *(float2*)&ob[(size_t)cp * HW2] = st;
    }
  }
}

// ---------------------------------------------------------------------------
extern "C" void kernel_launch(void* const* d_in, const int* in_sizes, int n_in,
                              void* d_out, int out_size, void* d_ws, size_t ws_size,
                              hipStream_t stream) {
  const float* x = (const float*)d_in[0];
  const float* cw = (const float*)d_in[1];
  const float* gamma = (const float*)d_in[2];
  const float* beta = (const float*)d_in[3];
  const float* mean = (const float*)d_in[4];
  const float* var = (const float*)d_in[5];
  const float* ew = (const float*)d_in[6];
  const float* eb = (const float*)d_in[7];
  float* out = (float*)d_out;

  unsigned short* Wb = (unsigned short*)d_ws;   // 73,728 bf16 (147,456 B)
  unsigned short* yt = Wb + (size_t)73728;      // 1,048,576 bf16 (2 MB)

  compress_kernel<<<BN * HH * 4, 256, 0, stream>>>(x, cw, gamma, beta, mean,
                                                   var, ew, Wb, yt);
  carafe_kernel<<<BN * HH * 4, 256, 0, stream>>>(x, Wb, yt, eb, out);
}